// Round 3
// baseline (607.295 us; speedup 1.0000x reference)
//
#include <hip/hip_runtime.h>

typedef _Float16 f16;
typedef f16 f16x4 __attribute__((ext_vector_type(4)));
typedef f16 f16x8 __attribute__((ext_vector_type(8)));
typedef float f32x4 __attribute__((ext_vector_type(4)));

#define T_STEPS 512
#define INPUT   12
#define HID     20
#define KDIM    32           // 12 + 20 == MFMA K exactly
#define BSTRIDE 40           // padded row stride (f16) -> conflict-free b128 reads
#define BATCH   16           // batches per group (MFMA N)
#define NTILES  5            // 5 x 16 gate-rows = 80 = 4*H
#define NGRP    2            // independent batch-groups per wave (ILP-2)

// intra-wave LDS RAW fence: no barrier needed (single wave per block).
// ONE fence per time step, covering BOTH groups — never between groups.
static __device__ __forceinline__ void lds_fence() {
    asm volatile("s_waitcnt lgkmcnt(0)" ::: "memory");
}

__global__ __launch_bounds__(64) void lstm_kernel(
    const float* __restrict__ x,      // [8192,512,12]
    const float* __restrict__ w_ih,   // [80,12]
    const float* __restrict__ w_hh,   // [80,20]
    const float* __restrict__ b_ih,   // [80]
    const float* __restrict__ b_hh,   // [80]
    const float* __restrict__ w_out,  // [10,20]
    const float* __restrict__ b_out,  // [10]
    float* __restrict__ out)          // [8192,10]
{
    // Row-permuted combined weights, pre-scaled by -log2(e) (sigmoid gates) or
    // +2*log2(e) (g gate). Tile w row r: gate (r&3) of unit 4w+(r>>2) ->
    // lane (quad,col) acc regs 0..3 = i,f,g,o of unit 4w+quad for batch col.
    __shared__ __align__(16) f16 Wc[80][KDIM];                       // 5 KB
    __shared__ __align__(16) f16 Bbuf[NGRP][2][BATCH][BSTRIDE];      // 5 KB

    const int lane = threadIdx.x;
    const int b    = lane & 15;        // MFMA N index = batch (also A-operand m index)
    const int quad = lane >> 4;

    // ---- build permuted, pre-scaled weight matrix (once, 40 iters) ----
    for (int i = lane; i < 80 * KDIM; i += 64) {
        int n = i >> 5, k = i & 31;
        int g = n & 3;                       // gate (i,f,g,o)
        int u = 4 * (n >> 4) + ((n >> 2) & 3);
        int row = g * HID + u;               // original row of [w_ih | w_hh]
        float v = (k < INPUT) ? w_ih[row * INPUT + k] : w_hh[row * HID + (k - INPUT)];
        float sc = (g == 2) ? 2.8853900817779268f : -1.4426950408889634f;
        Wc[n][k] = (f16)(v * sc);
    }

    // ---- scaled combined bias as MFMA C operand, unit u = 4w+quad ----
    f32x4 cbias[NTILES];
#pragma unroll
    for (int w = 0; w < NTILES; ++w) {
        int u = 4 * w + quad;
#pragma unroll
        for (int g = 0; g < 4; ++g) {
            float sc = (g == 2) ? 2.8853900817779268f : -1.4426950408889634f;
            cbias[w][g] = sc * (b_ih[g * HID + u] + b_hh[g * HID + u]);
        }
    }

    // zero h(-1) region of buf 0, both groups
#pragma unroll
    for (int g = 0; g < NGRP; ++g)
#pragma unroll
        for (int w = 0; w < NTILES; ++w)
            Bbuf[g][0][b][INPUT + 4 * w + quad] = (f16)0.f;

    // ---- x loaders: quads 0..2, lane (q,b) owns x[batch][t][4q..4q+3] ----
    const bool xload = quad < 3;
    const float* xp0 = x + (size_t)(blockIdx.x * (BATCH * NGRP) + 0 * BATCH + b) * (T_STEPS * INPUT) + 4 * quad;
    const float* xp1 = x + (size_t)(blockIdx.x * (BATCH * NGRP) + 1 * BATCH + b) * (T_STEPS * INPUT) + 4 * quad;

    f32x4 z4 = {0.f, 0.f, 0.f, 0.f};
    f32x4 q00 = z4, q01 = z4, q02 = z4, q03 = z4;   // group 0 queue: x(t+1..t+4)
    f32x4 q10 = z4, q11 = z4, q12 = z4, q13 = z4;   // group 1 queue
    if (xload) {
        f32x4 xa = *(const f32x4*)xp0;
        f32x4 xb = *(const f32x4*)xp1;
        f16x4 xc0, xc1;
#pragma unroll
        for (int j = 0; j < 4; ++j) { xc0[j] = (f16)xa[j]; xc1[j] = (f16)xb[j]; }
        *(f16x4*)&Bbuf[0][0][b][4 * quad] = xc0;     // stage x(0)
        *(f16x4*)&Bbuf[1][0][b][4 * quad] = xc1;
        q00 = *(const f32x4*)(xp0 + 1 * INPUT);
        q01 = *(const f32x4*)(xp0 + 2 * INPUT);
        q02 = *(const f32x4*)(xp0 + 3 * INPUT);
        q03 = *(const f32x4*)(xp0 + 4 * INPUT);
        q10 = *(const f32x4*)(xp1 + 1 * INPUT);
        q11 = *(const f32x4*)(xp1 + 2 * INPUT);
        q12 = *(const f32x4*)(xp1 + 3 * INPUT);
        q13 = *(const f32x4*)(xp1 + 4 * INPUT);
    }

    lds_fence();                                 // Wc + x(0) + h(-1) visible (same wave)

    // ---- stationary A fragments (shared by both groups) ----
    f16x8 afrag[NTILES];
#pragma unroll
    for (int w = 0; w < NTILES; ++w)
        afrag[w] = *(const f16x8*)&Wc[16 * w + b][quad * 8];

    float cc0[NTILES] = {0.f, 0.f, 0.f, 0.f, 0.f};
    float cc1[NTILES] = {0.f, 0.f, 0.f, 0.f, 0.f};

    // one dual time step: both groups between a single pair of fences.
    auto dual_step = [&](int pj, f32x4& qA, f32x4& qB, int tload) {
        lds_fence();                             // h(t-1)/x(t) writes (both groups) done
        f16x8 bf0 = *(const f16x8*)&Bbuf[0][pj][b][quad * 8];
        f16x8 bf1 = *(const f16x8*)&Bbuf[1][pj][b][quad * 8];

        // stage x(t+1) into next buffer; reload queue slot with x(t+5)
        if (xload) {
            f16x4 xc0, xc1;
#pragma unroll
            for (int j = 0; j < 4; ++j) { xc0[j] = (f16)qA[j]; xc1[j] = (f16)qB[j]; }
            *(f16x4*)&Bbuf[0][pj ^ 1][b][4 * quad] = xc0;
            *(f16x4*)&Bbuf[1][pj ^ 1][b][4 * quad] = xc1;
            int tl = tload < T_STEPS ? tload : T_STEPS - 1;
            qA = *(const f32x4*)(xp0 + (size_t)tl * INPUT);
            qB = *(const f32x4*)(xp1 + (size_t)tl * INPUT);
        }

        // 10 independent MFMAs (same A fragments, two B fragments)
        f32x4 acc0[NTILES], acc1[NTILES];
#pragma unroll
        for (int w = 0; w < NTILES; ++w) {
            acc0[w] = __builtin_amdgcn_mfma_f32_16x16x32_f16(afrag[w], bf0, cbias[w], 0, 0, 0);
            acc1[w] = __builtin_amdgcn_mfma_f32_16x16x32_f16(afrag[w], bf1, cbias[w], 0, 0, 0);
        }

        // fused activations, 7 transcendentals/unit, both groups interleaved:
        //   c = (c*Ai*Ag + (eg-1)*Af) / (Ai*Af*Ag)   [1 rcp]
        //   h = (et-1)/(At*Ao), et=2^(2.89c)          [1 rcp]
#pragma unroll
        for (int w = 0; w < NTILES; ++w) {
            {
                float ei = __builtin_amdgcn_exp2f(acc0[w][0]);
                float ef = __builtin_amdgcn_exp2f(acc0[w][1]);
                float eg = __builtin_amdgcn_exp2f(acc0[w][2]);
                float eo = __builtin_amdgcn_exp2f(acc0[w][3]);
                float Ai = 1.f + ei, Af = 1.f + ef, Ag = 1.f + eg, Ao = 1.f + eo;
                float P  = Ai * Ag;
                float rD = __builtin_amdgcn_rcpf(P * Af);
                float nm = __builtin_fmaf(eg - 1.f, Af, cc0[w] * P);
                float c  = nm * rD;
                cc0[w] = c;
                float et = __builtin_amdgcn_exp2f(2.8853900817779268f * c);
                float At = 1.f + et;
                float rM = __builtin_amdgcn_rcpf(At * Ao);
                float h  = (et - 1.f) * rM;
                Bbuf[0][pj ^ 1][b][INPUT + 4 * w + quad] = (f16)h;
            }
            {
                float ei = __builtin_amdgcn_exp2f(acc1[w][0]);
                float ef = __builtin_amdgcn_exp2f(acc1[w][1]);
                float eg = __builtin_amdgcn_exp2f(acc1[w][2]);
                float eo = __builtin_amdgcn_exp2f(acc1[w][3]);
                float Ai = 1.f + ei, Af = 1.f + ef, Ag = 1.f + eg, Ao = 1.f + eo;
                float P  = Ai * Ag;
                float rD = __builtin_amdgcn_rcpf(P * Af);
                float nm = __builtin_fmaf(eg - 1.f, Af, cc1[w] * P);
                float c  = nm * rD;
                cc1[w] = c;
                float et = __builtin_amdgcn_exp2f(2.8853900817779268f * c);
                float At = 1.f + et;
                float rM = __builtin_amdgcn_rcpf(At * Ao);
                float h  = (et - 1.f) * rM;
                Bbuf[1][pj ^ 1][b][INPUT + 4 * w + quad] = (f16)h;
            }
        }
    };

#pragma unroll 1
    for (int t4 = 0; t4 < T_STEPS; t4 += 4) {
        dual_step(0, q00, q10, t4 + 5);
        dual_step(1, q01, q11, t4 + 6);
        dual_step(0, q02, q12, t4 + 7);
        dual_step(1, q03, q13, t4 + 8);
    }

    lds_fence();                                 // h(T-1) writes (into buf 0) complete

    // ---- output projection: 32 batches x 10 outputs over 64 lanes ----
    for (int i = lane; i < BATCH * NGRP * 10; i += 64) {
        int bb = i / 10, oo = i - 10 * bb;
        int g  = bb >> 4, ob = bb & 15;
        float s = b_out[oo];
#pragma unroll
        for (int u2 = 0; u2 < HID; ++u2)
            s += w_out[oo * HID + u2] * (float)Bbuf[g][0][ob][INPUT + u2];
        out[(size_t)(blockIdx.x * (BATCH * NGRP) + bb) * 10 + oo] = s;
    }
}

extern "C" void kernel_launch(void* const* d_in, const int* in_sizes, int n_in,
                              void* d_out, int out_size, void* d_ws, size_t ws_size,
                              hipStream_t stream) {
    const float* x     = (const float*)d_in[0];
    const float* w_ih  = (const float*)d_in[1];
    const float* w_hh  = (const float*)d_in[2];
    const float* b_ih  = (const float*)d_in[3];
    const float* b_hh  = (const float*)d_in[4];
    const float* w_out = (const float*)d_in[5];
    const float* b_out = (const float*)d_in[6];
    float* out = (float*)d_out;

    const int blocks = 8192 / (BATCH * NGRP);   // 256 independent single-wave blocks
    hipLaunchKernelGGL(lstm_kernel, dim3(blocks), dim3(64), 0, stream,
                       x, w_ih, w_hh, b_ih, b_hh, w_out, b_out, out);
}

// Round 4
// 493.170 us; speedup vs baseline: 1.2314x; 1.2314x over previous
//
#include <hip/hip_runtime.h>

typedef _Float16 f16;
typedef f16 f16x8 __attribute__((ext_vector_type(8)));
typedef float f32x4 __attribute__((ext_vector_type(4)));
typedef unsigned int u32;
typedef unsigned short u16;

#define T_STEPS 512
#define INPUT   12
#define HID     20
#define KDIM    32           // 12 + 20 == MFMA K exactly
#define BATCH   16           // batches per wave (MFMA N)
#define NTILES  5            // 5 x 16 gate-rows = 80 = 4*H

static __device__ __forceinline__ f16 u16_as_f16(u16 v) {
    union { u16 u; f16 h; } cv; cv.u = v; return cv.h;
}
static __device__ __forceinline__ u16 f16_as_u16(f16 h) {
    union { u16 u; f16 h; } cv; cv.h = h; return cv.u;
}

// unit ownership: lane-quad q owns 5 units chosen so its OWN B-slice
// (k = 8q..8q+7 -> units 8q-12..8q-5) is mostly self-computed:
//   q0: {9,10,11,17,18}  (B-slice is pure x; owns everyone's leftovers)
//   q1: {0,1,2,3,19}     (B-slice x8-11 + u0-3: all own)
//   q2: {4,5,6,7,8}      (B-slice u4-11: 5 own + u9,10,11 from q0)
//   q3: {12,13,14,15,16} (B-slice u12-19: 5 own + u17,18 (q0), u19 (q1))
static __device__ __forceinline__ int own_unit(int mq, int w) {
    return (mq == 0) ? (w < 3 ? 9 + w : 14 + w)
         : (mq == 1) ? (w < 4 ? w : 19)
         : (mq == 2) ? (4 + w)
         : (12 + w);
}

__global__ __launch_bounds__(64) void lstm_kernel(
    const float* __restrict__ x,      // [8192,512,12]
    const float* __restrict__ w_ih,   // [80,12]
    const float* __restrict__ w_hh,   // [80,20]
    const float* __restrict__ b_ih,   // [80]
    const float* __restrict__ b_hh,   // [80]
    const float* __restrict__ w_out,  // [10,20]
    const float* __restrict__ b_out,  // [10]
    float* __restrict__ out)          // [8192,10]
{
    // LDS used ONLY for one-time weight staging (no per-step LDS traffic).
    __shared__ __align__(16) f16 Wc[NTILES][16][KDIM];   // 5 KB

    const int lane = threadIdx.x;
    const int c    = lane & 15;        // batch column (MFMA N, and A-row)
    const int q    = lane >> 4;        // k-slice / D-row-quad

    // ---- build permuted, pre-scaled weight tiles (once, 40 iters) ----
    // Tile w row m (= 4*mq + r): gate r of unit own_unit(mq, w).
    // Rows pre-scaled by -log2(e) (sigmoid gates r!=2) or +2*log2(e) (g gate).
    for (int i = lane; i < NTILES * 16 * KDIM; i += 64) {
        int w  = i >> 9;               // /512
        int m  = (i >> 5) & 15;
        int k  = i & 31;
        int mq = m >> 2, r = m & 3;
        int u  = own_unit(mq, w);
        int row = r * HID + u;         // original row of [w_ih | w_hh]
        float v = (k < INPUT) ? w_ih[row * INPUT + k] : w_hh[row * HID + (k - INPUT)];
        float sc = (r == 2) ? 2.8853900817779268f : -1.4426950408889634f;
        Wc[w][m][k] = (f16)(v * sc);
    }

    // ---- per-lane owned units + scaled bias as MFMA C operand ----
    int own[NTILES];
#pragma unroll
    for (int w = 0; w < NTILES; ++w) own[w] = own_unit(q, w);

    f32x4 cbias[NTILES];
#pragma unroll
    for (int w = 0; w < NTILES; ++w) {
#pragma unroll
        for (int r = 0; r < 4; ++r) {
            float sc = (r == 2) ? 2.8853900817779268f : -1.4426950408889634f;
            cbias[w][r] = sc * (b_ih[r * HID + own[w]] + b_hh[r * HID + own[w]]);
        }
    }

    // ---- per-lane x pointers (no LDS for x) ----
    // slot A: q0/q2/q3 -> x[c][t][0..3] (dup harmless), q1 -> x[c][t][8..11]
    // slot B: all lanes -> x[c][t][4..7] (only q0 consumes)
    const float* xbase = x + (size_t)(blockIdx.x * BATCH + c) * (T_STEPS * INPUT);
    const float* xptrA = xbase + (q == 1 ? 8 : 0);
    const float* xptrB = xbase + 4;

    // ---- recurrent state: all in registers ----
    f16   h16[NTILES] = {(f16)0.f, (f16)0.f, (f16)0.f, (f16)0.f, (f16)0.f};
    float cc[NTILES]  = {0.f, 0.f, 0.f, 0.f, 0.f};

    // assemble next B fragment from own h16, 4 ds_bpermutes, and x regs
    const int idx0 = 4 * c;            // lane (q=0, c)
    const int idx1 = 4 * (16 + c);     // lane (q=1, c)
    auto assemble = [&](f32x4 xA, f32x4 xB) -> f16x8 {
        u32 pk01 = (u32)f16_as_u16(h16[0]) | ((u32)f16_as_u16(h16[1]) << 16);
        u32 pk23 = (u32)f16_as_u16(h16[2]) | ((u32)f16_as_u16(h16[3]) << 16);
        u32 pk44 = (u32)f16_as_u16(h16[4]);
        u32 P1 = (u32)__builtin_amdgcn_ds_bpermute(idx0, (int)pk01); // (h9 ,h10)
        u32 P2 = (u32)__builtin_amdgcn_ds_bpermute(idx0, (int)pk23); // (h11,h17)
        u32 P3 = (u32)__builtin_amdgcn_ds_bpermute(idx0, (int)pk44); // (h18, - )
        u32 P4 = (u32)__builtin_amdgcn_ds_bpermute(idx1, (int)pk44); // (h19, - )

        f16 xf[8];
#pragma unroll
        for (int j = 0; j < 4; ++j) { xf[j] = (f16)xA[j]; xf[4 + j] = (f16)xB[j]; }

        const bool is0 = (q == 0), is1 = (q == 1), is2 = (q == 2), le1 = (q <= 1);
        f16 hb[8];
        hb[0] = le1 ? xf[0] : h16[0];
        hb[1] = le1 ? xf[1] : h16[1];
        hb[2] = le1 ? xf[2] : h16[2];
        hb[3] = le1 ? xf[3] : h16[3];
        hb[4] = is0 ? xf[4] : (is1 ? h16[0] : h16[4]);
        hb[5] = is0 ? xf[5] : (is1 ? h16[1] : (is2 ? u16_as_f16((u16)P1)
                                                   : u16_as_f16((u16)(P2 >> 16))));
        hb[6] = is0 ? xf[6] : (is1 ? h16[2] : (is2 ? u16_as_f16((u16)(P1 >> 16))
                                                   : u16_as_f16((u16)P3)));
        hb[7] = is0 ? xf[7] : (is1 ? h16[3] : (is2 ? u16_as_f16((u16)P2)
                                                   : u16_as_f16((u16)P4)));
        f16x8 r;
#pragma unroll
        for (int j = 0; j < 8; ++j) r[j] = hb[j];
        return r;
    };

    // ---- prologue: x(0) + 4-deep prefetch queue x(1..4) ----
    f32x4 x0A = *(const f32x4*)xptrA;
    f32x4 x0B = *(const f32x4*)xptrB;
    f32x4 qA0 = *(const f32x4*)(xptrA + 1 * INPUT), qB0 = *(const f32x4*)(xptrB + 1 * INPUT);
    f32x4 qA1 = *(const f32x4*)(xptrA + 2 * INPUT), qB1 = *(const f32x4*)(xptrB + 2 * INPUT);
    f32x4 qA2 = *(const f32x4*)(xptrA + 3 * INPUT), qB2 = *(const f32x4*)(xptrB + 3 * INPUT);
    f32x4 qA3 = *(const f32x4*)(xptrA + 4 * INPUT), qB3 = *(const f32x4*)(xptrB + 4 * INPUT);

    asm volatile("s_waitcnt lgkmcnt(0)" ::: "memory");   // Wc staging complete

    // stationary A fragments: A[m=c][k=8q+j] of each tile
    f16x8 afrag[NTILES];
#pragma unroll
    for (int w = 0; w < NTILES; ++w)
        afrag[w] = *(const f16x8*)&Wc[w][c][q * 8];

    f16x8 bfrag = assemble(x0A, x0B);                    // t=0 (h(-1)=0)

    // one recurrence step: MFMA -> activations -> assemble next B fragment
    auto step = [&](f32x4& sA, f32x4& sB, int tload) {
        f32x4 acc[NTILES];
#pragma unroll
        for (int w = 0; w < NTILES; ++w)
            acc[w] = __builtin_amdgcn_mfma_f32_16x16x32_f16(afrag[w], bfrag, cbias[w], 0, 0, 0);

        // prefetch x(t+5) early (consumed 4 steps later)
        int tl = tload < T_STEPS ? tload : T_STEPS - 1;
        f32x4 nA = *(const f32x4*)(xptrA + (size_t)tl * INPUT);
        f32x4 nB = *(const f32x4*)(xptrB + (size_t)tl * INPUT);

        // fused activations (7 transcendentals/unit):
        //   c' = (c*Ai*Ag + (eg-1)*Af) / (Ai*Af*Ag)   [1 rcp]
        //   h  = (et-1)/(At*Ao), et = 2^(2.885*c')    [1 rcp]
#pragma unroll
        for (int w = 0; w < NTILES; ++w) {
            float ei = __builtin_amdgcn_exp2f(acc[w][0]);
            float ef = __builtin_amdgcn_exp2f(acc[w][1]);
            float eg = __builtin_amdgcn_exp2f(acc[w][2]);
            float eo = __builtin_amdgcn_exp2f(acc[w][3]);
            float Ai = 1.f + ei, Af = 1.f + ef, Ag = 1.f + eg, Ao = 1.f + eo;
            float P  = Ai * Ag;
            float rD = __builtin_amdgcn_rcpf(P * Af);
            float nm = __builtin_fmaf(eg - 1.f, Af, cc[w] * P);
            float cn = nm * rD;
            cc[w] = cn;
            float et = __builtin_amdgcn_exp2f(2.8853900817779268f * cn);
            float At = 1.f + et;
            float rM = __builtin_amdgcn_rcpf(At * Ao);
            h16[w] = (f16)((et - 1.f) * rM);
        }

        bfrag = assemble(sA, sB);      // build B(t+1) from fresh h + queued x(t+1)
        sA = nA; sB = nB;              // rotate queue slot to x(t+5)
    };

#pragma unroll 1
    for (int t4 = 0; t4 < T_STEPS; t4 += 4) {
        step(qA0, qB0, t4 + 5);
        step(qA1, qB1, t4 + 6);
        step(qA2, qB2, t4 + 7);
        step(qA3, qB3, t4 + 8);
    }
    // (body 511 assembles an unused bfrag from clamped x — harmless)

    // ---- output projection: each lane holds h(511) of its 5 units ----
    float po[10];
#pragma unroll
    for (int o = 0; o < 10; ++o) {
        float s = 0.f;
#pragma unroll
        for (int w = 0; w < NTILES; ++w)
            s += w_out[o * HID + own[w]] * (float)h16[w];
        po[o] = s;
    }
    // reduce across the 4 quads holding the same batch column c
#pragma unroll
    for (int o = 0; o < 10; ++o) {
        po[o] += __shfl_xor(po[o], 16);
        po[o] += __shfl_xor(po[o], 32);
    }
    if (q < 2) {
#pragma unroll
        for (int i = 0; i < 5; ++i) {
            int o = 5 * q + i;
            out[(size_t)(blockIdx.x * BATCH + c) * 10 + o] = po[o] + b_out[o];
        }
    }
}

extern "C" void kernel_launch(void* const* d_in, const int* in_sizes, int n_in,
                              void* d_out, int out_size, void* d_ws, size_t ws_size,
                              hipStream_t stream) {
    const float* x     = (const float*)d_in[0];
    const float* w_ih  = (const float*)d_in[1];
    const float* w_hh  = (const float*)d_in[2];
    const float* b_ih  = (const float*)d_in[3];
    const float* b_hh  = (const float*)d_in[4];
    const float* w_out = (const float*)d_in[5];
    const float* b_out = (const float*)d_in[6];
    float* out = (float*)d_out;

    const int blocks = 8192 / BATCH;   // 512 independent single-wave blocks
    hipLaunchKernelGGL(lstm_kernel, dim3(blocks), dim3(64), 0, stream,
                       x, w_ih, w_hh, b_ih, b_hh, w_out, b_out, out);
}

// Round 5
// 434.377 us; speedup vs baseline: 1.3981x; 1.1353x over previous
//
#include <hip/hip_runtime.h>

typedef _Float16 f16;
typedef f16 f16x4 __attribute__((ext_vector_type(4)));
typedef f16 f16x8 __attribute__((ext_vector_type(8)));
typedef float f32x4 __attribute__((ext_vector_type(4)));

#define T_STEPS 512
#define INPUT   12
#define HID     20
#define KDIM    32           // 12 + 20 == MFMA K exactly
#define BSTRIDE 40           // padded row stride (f16) -> low-conflict b128 reads
#define BATCH   16           // batches per block (MFMA N)
#define BLOCK   128          // 2 waves: wave0 = tiles 0..2, wave1 = tiles 3..4 + x-duty

// drain LDS writes then rendezvous both waves (x prefetch stays on vmcnt)
static __device__ __forceinline__ void block_barrier() {
    asm volatile("s_waitcnt lgkmcnt(0)\n\ts_barrier" ::: "memory");
}

__global__ __launch_bounds__(BLOCK) void lstm_kernel(
    const float* __restrict__ x,      // [8192,512,12]
    const float* __restrict__ w_ih,   // [80,12]
    const float* __restrict__ w_hh,   // [80,20]
    const float* __restrict__ b_ih,   // [80]
    const float* __restrict__ b_hh,   // [80]
    const float* __restrict__ w_out,  // [10,20]
    const float* __restrict__ b_out,  // [10]
    float* __restrict__ out)          // [8192,10]
{
    // Row-permuted combined weights, pre-scaled by -log2(e) (sigmoid gates) or
    // +2*log2(e) (g gate). Tile t row m: gate (m&3) of unit 4t+(m>>2) ->
    // lane (q,c) acc regs 0..3 = i,f,g,o of unit 4t+q for batch c.
    __shared__ __align__(16) f16 Wc[80][KDIM];                 // 5 KB
    __shared__ __align__(16) f16 Bbuf[2][BATCH][BSTRIDE];      // 2.5 KB, [x(12)|h(20)|pad]

    const int tid  = threadIdx.x;
    const int wid  = tid >> 6;
    const int lane = tid & 63;
    const int c    = lane & 15;        // batch column (MFMA N, and A-row m)
    const int q    = lane >> 4;        // k-slice / D-row-quad

    // ---- build permuted, pre-scaled weight matrix (once, 20 iters) ----
    for (int i = tid; i < 80 * KDIM; i += BLOCK) {
        int n = i >> 5, k = i & 31;
        int g = n & 3;                       // gate (i,f,g,o)
        int u = 4 * (n >> 4) + ((n >> 2) & 3);
        int row = g * HID + u;               // original row of [w_ih | w_hh]
        float v = (k < INPUT) ? w_ih[row * INPUT + k] : w_hh[row * HID + (k - INPUT)];
        float sc = (g == 2) ? 2.8853900817779268f : -1.4426950408889634f;
        Wc[n][k] = (f16)(v * sc);
    }

    // ---- per-wave tile assignment ----
    const int TBASE = wid ? 3 : 0;     // wave0: tiles 0,1,2  wave1: tiles 3,4
    const int TCNT  = wid ? 2 : 3;

    int   uu[3]    = {0, 0, 0};
    f32x4 cbias[3] = {};
    float cc[3]    = {0.f, 0.f, 0.f};
#pragma unroll
    for (int j = 0; j < 3; ++j)
        if (j < TCNT) {
            uu[j] = 4 * (TBASE + j) + q;
#pragma unroll
            for (int r = 0; r < 4; ++r) {
                float sc = (r == 2) ? 2.8853900817779268f : -1.4426950408889634f;
                cbias[j][r] = sc * (b_ih[r * HID + uu[j]] + b_hh[r * HID + uu[j]]);
            }
            Bbuf[0][c][INPUT + uu[j]] = (f16)0.f;   // zero own h(-1) entries
        }

    // ---- x stager: wave1 lanes 0..47, lane -> (batch cb, 4-float slice p) ----
    const bool stage = (wid == 1) && (lane < 48);
    const int  l3 = stage ? lane : 0;
    const int  cb = l3 / 3, p = l3 - 3 * cb;
    const float* xptr = x + (size_t)(blockIdx.x * BATCH + cb) * (T_STEPS * INPUT) + 4 * p;

    f32x4 z4 = {0.f, 0.f, 0.f, 0.f};
    f32x4 qq0 = z4, qq1 = z4, qq2 = z4, qq3 = z4;   // 4-deep x queue: x(t+1..t+4)
    if (stage) {
        f32x4 x0 = *(const f32x4*)xptr;              // x(0)
        f16x4 xc;
#pragma unroll
        for (int jj = 0; jj < 4; ++jj) xc[jj] = (f16)x0[jj];
        *(f16x4*)&Bbuf[0][cb][4 * p] = xc;
        qq0 = *(const f32x4*)(xptr + 1 * INPUT);
        qq1 = *(const f32x4*)(xptr + 2 * INPUT);
        qq2 = *(const f32x4*)(xptr + 3 * INPUT);
        qq3 = *(const f32x4*)(xptr + 4 * INPUT);
    }
    __syncthreads();                                 // Wc + x(0) + h(-1) visible

    // ---- stationary A fragments: A[m=c][k=8q+j] of each owned tile ----
    f16x8 afrag[3];
#pragma unroll
    for (int j = 0; j < 3; ++j)
        if (j < TCNT)
            afrag[j] = *(const f16x8*)&Wc[16 * (TBASE + j) + c][q * 8];

    // one recurrence step; pj = buffer parity (compile-time after inlining)
    auto step = [&](int pj, f32x4& qs, int tload) {
        // B fragment: B[k=8q+j][n=c] (16B read, issued right after barrier)
        f16x8 bfrag = *(const f16x8*)&Bbuf[pj][c][q * 8];

        // stage x(t+1) into next buffer; reload queue slot with x(t+5)
        if (stage) {
            f16x4 xc;
#pragma unroll
            for (int jj = 0; jj < 4; ++jj) xc[jj] = (f16)qs[jj];
            *(f16x4*)&Bbuf[pj ^ 1][cb][4 * p] = xc;
            int tl = tload < T_STEPS ? tload : T_STEPS - 1;
            qs = *(const f32x4*)(xptr + (size_t)tl * INPUT);
        }

        // owned gate tiles (wave0: 3, wave1: 2), independent MFMAs
        f32x4 acc[3];
#pragma unroll
        for (int j = 0; j < 3; ++j)
            if (j < TCNT)
                acc[j] = __builtin_amdgcn_mfma_f32_16x16x32_f16(afrag[j], bfrag, cbias[j], 0, 0, 0);

        // fused activations, 7 transcendentals/unit:
        //   c' = (c*Ai*Ag + (eg-1)*Af) / (Ai*Af*Ag)   [1 rcp]
        //   h  = (et-1)/(At*Ao), et = 2^(2.885*c')    [1 rcp]
#pragma unroll
        for (int j = 0; j < 3; ++j)
            if (j < TCNT) {
                float ei = __builtin_amdgcn_exp2f(acc[j][0]);
                float ef = __builtin_amdgcn_exp2f(acc[j][1]);
                float eg = __builtin_amdgcn_exp2f(acc[j][2]);
                float eo = __builtin_amdgcn_exp2f(acc[j][3]);
                float Ai = 1.f + ei, Af = 1.f + ef, Ag = 1.f + eg, Ao = 1.f + eo;
                float P  = Ai * Ag;
                float rD = __builtin_amdgcn_rcpf(P * Af);
                float nm = __builtin_fmaf(eg - 1.f, Af, cc[j] * P);
                float cn = nm * rD;
                cc[j] = cn;
                float et = __builtin_amdgcn_exp2f(2.8853900817779268f * cn);
                float At = 1.f + et;
                float rM = __builtin_amdgcn_rcpf(At * Ao);
                float h  = (et - 1.f) * rM;
                Bbuf[pj ^ 1][c][INPUT + uu[j]] = (f16)h;   // publish h(t)
            }

        block_barrier();                 // one 2-wave barrier per step
    };

#pragma unroll 1
    for (int t4 = 0; t4 < T_STEPS; t4 += 4) {
        step(0, qq0, t4 + 5);
        step(1, qq1, t4 + 6);
        step(0, qq2, t4 + 7);
        step(1, qq3, t4 + 8);
    }

    // ---- output projection: T even -> h(T-1) sits in Bbuf[0] ----
    for (int i = tid; i < BATCH * 10; i += BLOCK) {
        int ob = i / 10, oo = i - 10 * ob;
        float s = b_out[oo];
#pragma unroll
        for (int u2 = 0; u2 < HID; ++u2)
            s += w_out[oo * HID + u2] * (float)Bbuf[0][ob][INPUT + u2];
        out[(size_t)(blockIdx.x * BATCH + ob) * 10 + oo] = s;
    }
}

extern "C" void kernel_launch(void* const* d_in, const int* in_sizes, int n_in,
                              void* d_out, int out_size, void* d_ws, size_t ws_size,
                              hipStream_t stream) {
    const float* x     = (const float*)d_in[0];
    const float* w_ih  = (const float*)d_in[1];
    const float* w_hh  = (const float*)d_in[2];
    const float* b_ih  = (const float*)d_in[3];
    const float* b_hh  = (const float*)d_in[4];
    const float* w_out = (const float*)d_in[5];
    const float* b_out = (const float*)d_in[6];
    float* out = (float*)d_out;

    const int blocks = 8192 / BATCH;   // 512 blocks x 2 waves; 2 blocks/CU = 1 wave/SIMD
    hipLaunchKernelGGL(lstm_kernel, dim3(blocks), dim3(BLOCK), 0, stream,
                       x, w_ih, w_hh, b_ih, b_hh, w_out, b_out, out);
}

// Round 6
// 430.700 us; speedup vs baseline: 1.4100x; 1.0085x over previous
//
#include <hip/hip_runtime.h>

typedef _Float16 f16;
typedef f16 f16x8 __attribute__((ext_vector_type(8)));
typedef float f32x4 __attribute__((ext_vector_type(4)));

#define T_STEPS 512
#define INPUT   12
#define HID     20
#define KDIM    32           // 12 + 20 == MFMA K exactly
#define BSTRIDE 40           // padded row stride (f16) -> low-conflict b128 reads
#define BATCH   16           // batches per group (MFMA N)
#define NGRP    2            // groups per block -> 2 time steps per chain traversal
#define WPB     5            // 5 waves x 16 gate-rows = 80 = 4*H
#define BLOCK   (WPB * 64)

// drain LDS ops then rendezvous (x prefetch stays in flight on vmcnt)
static __device__ __forceinline__ void block_barrier() {
    asm volatile("s_waitcnt lgkmcnt(0)\n\ts_barrier" ::: "memory");
}

__global__ __launch_bounds__(BLOCK) void lstm_kernel(
    const float* __restrict__ x,      // [8192,512,12]
    const float* __restrict__ w_ih,   // [80,12]
    const float* __restrict__ w_hh,   // [80,20]
    const float* __restrict__ b_ih,   // [80]
    const float* __restrict__ b_hh,   // [80]
    const float* __restrict__ w_out,  // [10,20]
    const float* __restrict__ b_out,  // [10]
    float* __restrict__ out)          // [8192,10]
{
    // Row-permuted combined weights, pre-scaled by -log2(e) (sigmoid gates) or
    // +2*log2(e) (g gate). Wave w tile row m: gate (m&3) of unit 4w+(m>>2) ->
    // lane (q,c) acc regs 0..3 = i,f,g,o of unit 4w+q for batch c.
    __shared__ __align__(16) f16 Wc[80][KDIM];                       // 5 KB
    __shared__ __align__(16) f16 Bbuf[NGRP][2][BATCH][BSTRIDE];      // 5 KB

    const int tid  = threadIdx.x;
    const int wid  = tid >> 6;
    const int lane = tid & 63;
    const int c    = lane & 15;        // batch column (MFMA N, and A-row m)
    const int q    = lane >> 4;        // k-slice / D-row-quad

    // ---- build permuted, pre-scaled weight matrix (once, 8 iters) ----
    for (int i = tid; i < 80 * KDIM; i += BLOCK) {
        int n = i >> 5, k = i & 31;
        int g = n & 3;                       // gate (i,f,g,o)
        int u = 4 * (n >> 4) + ((n >> 2) & 3);
        int row = g * HID + u;               // original row of [w_ih | w_hh]
        float v = (k < INPUT) ? w_ih[row * INPUT + k] : w_hh[row * HID + (k - INPUT)];
        float sc = (g == 2) ? 2.8853900817779268f : -1.4426950408889634f;
        Wc[n][k] = (f16)(v * sc);
    }

    // ---- per-lane (batch, unit) ownership; bias shared by both groups ----
    const int u = 4 * wid + q;         // unit 0..19
    f32x4 cbias;
#pragma unroll
    for (int r = 0; r < 4; ++r) {
        float sc = (r == 2) ? 2.8853900817779268f : -1.4426950408889634f;
        cbias[r] = sc * (b_ih[r * HID + u] + b_hh[r * HID + u]);
    }

    // zero h(-1) region of buf 0, both groups
    Bbuf[0][0][c][INPUT + u] = (f16)0.f;
    Bbuf[1][0][c][INPUT + u] = (f16)0.f;

    // ---- x loaders: tids 0..191, one float per group per step ----
    const bool xload = tid < BATCH * INPUT;
    const int  xb    = tid / INPUT;
    const int  xi    = tid % INPUT;
    const float* xpA = x + (size_t)(blockIdx.x * (BATCH * NGRP) + xb) * (T_STEPS * INPUT) + xi;
    const float* xpB = xpA + (size_t)BATCH * (T_STEPS * INPUT);

    // 4-deep prefetch queues, one per group
    float qA0 = 0.f, qA1 = 0.f, qA2 = 0.f, qA3 = 0.f;
    float qB0 = 0.f, qB1 = 0.f, qB2 = 0.f, qB3 = 0.f;
    if (xload) {
        Bbuf[0][0][xb][xi] = (f16)xpA[0];        // stage x(0)
        Bbuf[1][0][xb][xi] = (f16)xpB[0];
        qA0 = xpA[1 * INPUT]; qB0 = xpB[1 * INPUT];
        qA1 = xpA[2 * INPUT]; qB1 = xpB[2 * INPUT];
        qA2 = xpA[3 * INPUT]; qB2 = xpB[3 * INPUT];
        qA3 = xpA[4 * INPUT]; qB3 = xpB[4 * INPUT];
    }
    __syncthreads();                             // Wc + x(0) + h(-1) visible

    // ---- constant A fragment: A[m=c][k=8q+j] from own wave's tile ----
    const f16x8 afragW = *(const f16x8*)&Wc[16 * wid + c][q * 8];

    float ccA = 0.f, ccB = 0.f;

    // one dual recurrence step: both groups inside one barrier interval
    auto step = [&](int pj, float& qA, float& qB, int tload) {
        // independent B fragments (pipelined b128 reads)
        f16x8 bfA = *(const f16x8*)&Bbuf[0][pj][c][q * 8];
        f16x8 bfB = *(const f16x8*)&Bbuf[1][pj][c][q * 8];

        // stage x(t+1) into next buffers; reload queue slots with x(t+5)
        if (xload) {
            Bbuf[0][pj ^ 1][xb][xi] = (f16)qA;
            Bbuf[1][pj ^ 1][xb][xi] = (f16)qB;
            int tl = tload < T_STEPS ? tload : T_STEPS - 1;
            qA = xpA[(size_t)tl * INPUT];
            qB = xpB[(size_t)tl * INPUT];
        }

        // two independent MFMAs sharing the stationary A fragment
        f32x4 aA = __builtin_amdgcn_mfma_f32_16x16x32_f16(afragW, bfA, cbias, 0, 0, 0);
        f32x4 aB = __builtin_amdgcn_mfma_f32_16x16x32_f16(afragW, bfB, cbias, 0, 0, 0);

        // fused activations (7 transcendentals/unit), groups interleave freely:
        //   c' = (c*Ai*Ag + (eg-1)*Af) / (Ai*Af*Ag)   [1 rcp]
        //   h  = (et-1)/(At*Ao), et = 2^(2.885*c')    [1 rcp]
        {
            float ei = __builtin_amdgcn_exp2f(aA[0]);
            float ef = __builtin_amdgcn_exp2f(aA[1]);
            float eg = __builtin_amdgcn_exp2f(aA[2]);
            float eo = __builtin_amdgcn_exp2f(aA[3]);
            float Ai = 1.f + ei, Af = 1.f + ef, Ag = 1.f + eg, Ao = 1.f + eo;
            float P  = Ai * Ag;
            float rD = __builtin_amdgcn_rcpf(P * Af);
            float nm = __builtin_fmaf(eg - 1.f, Af, ccA * P);
            float cn = nm * rD;
            ccA = cn;
            float et = __builtin_amdgcn_exp2f(2.8853900817779268f * cn);
            float At = 1.f + et;
            float rM = __builtin_amdgcn_rcpf(At * Ao);
            Bbuf[0][pj ^ 1][c][INPUT + u] = (f16)((et - 1.f) * rM);
        }
        {
            float ei = __builtin_amdgcn_exp2f(aB[0]);
            float ef = __builtin_amdgcn_exp2f(aB[1]);
            float eg = __builtin_amdgcn_exp2f(aB[2]);
            float eo = __builtin_amdgcn_exp2f(aB[3]);
            float Ai = 1.f + ei, Af = 1.f + ef, Ag = 1.f + eg, Ao = 1.f + eo;
            float P  = Ai * Ag;
            float rD = __builtin_amdgcn_rcpf(P * Af);
            float nm = __builtin_fmaf(eg - 1.f, Af, ccB * P);
            float cn = nm * rD;
            ccB = cn;
            float et = __builtin_amdgcn_exp2f(2.8853900817779268f * cn);
            float At = 1.f + et;
            float rM = __builtin_amdgcn_rcpf(At * Ao);
            Bbuf[1][pj ^ 1][c][INPUT + u] = (f16)((et - 1.f) * rM);
        }

        block_barrier();                         // one barrier per dual step
    };

#pragma unroll 1
    for (int t4 = 0; t4 < T_STEPS; t4 += 4) {
        step(0, qA0, qB0, t4 + 5);
        step(1, qA1, qB1, t4 + 6);
        step(0, qA2, qB2, t4 + 7);
        step(1, qA3, qB3, t4 + 8);
    }

    // ---- output projection: T even -> h(T-1) in Bbuf[g][0]; 320 outputs ----
    {
        int bb = tid / 10, oo = tid - 10 * bb;   // bb 0..31, oo 0..9
        int g  = bb >> 4, ob = bb & 15;
        float s = b_out[oo];
#pragma unroll
        for (int u2 = 0; u2 < HID; ++u2)
            s += w_out[oo * HID + u2] * (float)Bbuf[g][0][ob][INPUT + u2];
        out[(size_t)(blockIdx.x * (BATCH * NGRP) + bb) * 10 + oo] = s;
    }
}

extern "C" void kernel_launch(void* const* d_in, const int* in_sizes, int n_in,
                              void* d_out, int out_size, void* d_ws, size_t ws_size,
                              hipStream_t stream) {
    const float* x     = (const float*)d_in[0];
    const float* w_ih  = (const float*)d_in[1];
    const float* w_hh  = (const float*)d_in[2];
    const float* b_ih  = (const float*)d_in[3];
    const float* b_hh  = (const float*)d_in[4];
    const float* w_out = (const float*)d_in[5];
    const float* b_out = (const float*)d_in[6];
    float* out = (float*)d_out;

    const int blocks = 8192 / (BATCH * NGRP);   // 256 blocks x 5 waves; 1 block/CU
    hipLaunchKernelGGL(lstm_kernel, dim3(blocks), dim3(BLOCK), 0, stream,
                       x, w_ih, w_hh, b_ih, b_hh, w_out, b_out, out);
}